// Round 1
// baseline (38773.096 us; speedup 1.0000x reference)
//
#include <hip/hip_runtime.h>
#include <hip/hip_bf16.h>
#include <cstddef>

// Problem: GRU  B=32, L=1024, D_IN=512, H=512
// inputs: x(32,1024,512) f32, init_states(32,512) f32,
//         W_ru(1024,1024) f32 [cols 0:512 = Wh_ru, 512:1024 = Wx_ru],
//         b_ru(1024), W_c(512,1024) [cols 0:512 = Wh_c, 512:1024 = Wx_c], b_c(512)
// outputs: outs(32,1024,512) then h_last(32,512), flat in d_out.

#define Bsz   32
#define Lsz   1024
#define Hsz   512
#define NG    1536   // 1024 ru gates + 512 cand

__device__ __forceinline__ float sigmoidf_(float v) {
    return 1.0f / (1.0f + __expf(-v));
}
__device__ __forceinline__ float tanhf_(float v) {
    float e = __expf(2.0f * v);           // inf -> 1, 0 -> -1 : correct saturation
    return 1.0f - 2.0f / (e + 1.0f);
}

// ---------------- transpose weights to k-major -----------------------------
// dst[k*G + g] = src[g*S + k]   for g in [0,G), k in [0,K)
__global__ __launch_bounds__(256) void transpose_k(const float* __restrict__ src,
                                                   float* __restrict__ dst,
                                                   int G, int K, int S) {
    __shared__ float tile[32][33];
    int g0 = blockIdx.x * 32, k0 = blockIdx.y * 32;
    int lx = threadIdx.x & 31, ly = threadIdx.x >> 5;   // 32 x 8
    #pragma unroll
    for (int i = ly; i < 32; i += 8)
        tile[i][lx] = src[(size_t)(g0 + i) * S + (k0 + lx)];
    __syncthreads();
    #pragma unroll
    for (int i = ly; i < 32; i += 8)
        dst[(size_t)(k0 + i) * G + (g0 + lx)] = tile[lx][i];
}

__global__ __launch_bounds__(256) void init_h(const float* __restrict__ h0,
                                              float* __restrict__ hstate) {
    int i = blockIdx.x * 256 + threadIdx.x;
    hstate[i] = h0[i];
}

// ---------------- input-projection GEMM ------------------------------------
// pre[(t_local*32+b)*1536 + n] = sum_k x[b, t0+t_local, k] * Wx[n][k] + bias[n]
// 128x128 tile, BK=8, 256 threads, 8x8 per thread.
__global__ __launch_bounds__(256) void gemm_pre(const float* __restrict__ x,
                                                const float* __restrict__ W_ru,
                                                const float* __restrict__ b_ru,
                                                const float* __restrict__ W_c,
                                                const float* __restrict__ b_c,
                                                float* __restrict__ pre,
                                                int t0) {
    __shared__ float As[8][128];
    __shared__ float Bs[8][128];
    const int tid = threadIdx.x;
    const int bm = blockIdx.x, bn = blockIdx.y;
    const int tx = tid & 15, ty = tid >> 4;

    // cooperative load indices: 2 threads per row, float4 each
    const int lrow = tid >> 1;
    const int lk4  = (tid & 1) * 4;
    const int grow = bm * 128 + lrow;          // row within chunk = t_local*32 + b
    const int tt = grow >> 5, bb = grow & 31;
    const float* xrow = x + ((size_t)bb * Lsz + (t0 + tt)) * 512;
    const int gn = bn * 128 + lrow;            // output column (gate index)
    const float* wrow = (gn < 1024) ? (W_ru + (size_t)gn * 1024 + 512)
                                    : (W_c  + (size_t)(gn - 1024) * 1024 + 512);

    float acc[8][8];
    #pragma unroll
    for (int i = 0; i < 8; ++i)
        #pragma unroll
        for (int j = 0; j < 8; ++j) acc[i][j] = 0.0f;

    for (int k0 = 0; k0 < 512; k0 += 8) {
        float4 av = *(const float4*)(xrow + k0 + lk4);
        float4 bv = *(const float4*)(wrow + k0 + lk4);
        __syncthreads();
        As[lk4 + 0][lrow] = av.x; As[lk4 + 1][lrow] = av.y;
        As[lk4 + 2][lrow] = av.z; As[lk4 + 3][lrow] = av.w;
        Bs[lk4 + 0][lrow] = bv.x; Bs[lk4 + 1][lrow] = bv.y;
        Bs[lk4 + 2][lrow] = bv.z; Bs[lk4 + 3][lrow] = bv.w;
        __syncthreads();
        #pragma unroll
        for (int k = 0; k < 8; ++k) {
            float a[8], b[8];
            *(float4*)&a[0] = *(const float4*)&As[k][ty * 8];
            *(float4*)&a[4] = *(const float4*)&As[k][ty * 8 + 4];
            *(float4*)&b[0] = *(const float4*)&Bs[k][tx * 8];
            *(float4*)&b[4] = *(const float4*)&Bs[k][tx * 8 + 4];
            #pragma unroll
            for (int i = 0; i < 8; ++i)
                #pragma unroll
                for (int j = 0; j < 8; ++j)
                    acc[i][j] += a[i] * b[j];
        }
    }

    const int row0 = bm * 128 + ty * 8;
    const int col0 = bn * 128 + tx * 8;
    float bias[8];
    #pragma unroll
    for (int j = 0; j < 8; ++j) {
        int c = col0 + j;
        bias[j] = (c < 1024) ? b_ru[c] : b_c[c - 1024];
    }
    #pragma unroll
    for (int i = 0; i < 8; ++i) {
        float4 v0 = make_float4(acc[i][0] + bias[0], acc[i][1] + bias[1],
                                acc[i][2] + bias[2], acc[i][3] + bias[3]);
        float4 v1 = make_float4(acc[i][4] + bias[4], acc[i][5] + bias[5],
                                acc[i][6] + bias[6], acc[i][7] + bias[7]);
        float* p = pre + (size_t)(row0 + i) * NG + col0;
        *(float4*)p = v0;
        *(float4*)(p + 4) = v1;
    }
}

// ---------------- sequential recurrence ------------------------------------
// One workgroup (512 threads) per batch. h in LDS. Weights pre-transposed:
//   WtR[k*1024 + g] = Wh_ru[g][k]   (k-major, coalesced float2 per lane)
//   WtC[k*512  + j] = Wh_c[j][k]
__global__ __launch_bounds__(512) void gru_rec(const float* __restrict__ WtR,
                                               const float* __restrict__ WtC,
                                               const float* __restrict__ pre,
                                               float* __restrict__ hstate,
                                               float* __restrict__ out,
                                               float* __restrict__ hlast,
                                               int t0, int Tc) {
    __shared__ float h_s[512];
    __shared__ float rh_s[512];
    __shared__ float z_s[512];
    const int b = blockIdx.x;
    const int tid = threadIdx.x;

    h_s[tid] = hstate[b * 512 + tid];
    __syncthreads();

    for (int t = 0; t < Tc; ++t) {
        const float* prow = pre + ((size_t)t * Bsz + b) * NG;

        // ---- gates: this thread owns columns 2*tid, 2*tid+1 of the 1024 ru gates
        float acc0 = 0.0f, acc1 = 0.0f;
        for (int k = 0; k < 512; k += 4) {
            float4 h4 = *(const float4*)&h_s[k];
            float2 w0 = *(const float2*)&WtR[(size_t)(k + 0) * 1024 + 2 * tid];
            float2 w1 = *(const float2*)&WtR[(size_t)(k + 1) * 1024 + 2 * tid];
            float2 w2 = *(const float2*)&WtR[(size_t)(k + 2) * 1024 + 2 * tid];
            float2 w3 = *(const float2*)&WtR[(size_t)(k + 3) * 1024 + 2 * tid];
            acc0 += w0.x * h4.x + w1.x * h4.y + w2.x * h4.z + w3.x * h4.w;
            acc1 += w0.y * h4.x + w1.y * h4.y + w2.y * h4.z + w3.y * h4.w;
        }
        float2 xg = *(const float2*)&prow[2 * tid];
        float g0 = sigmoidf_(acc0 + xg.x);
        float g1 = sigmoidf_(acc1 + xg.y);
        if (tid < 256) {                       // r gates -> r*h
            rh_s[2 * tid]     = g0 * h_s[2 * tid];
            rh_s[2 * tid + 1] = g1 * h_s[2 * tid + 1];
        } else {                               // z gates
            z_s[2 * tid - 512] = g0;
            z_s[2 * tid - 511] = g1;
        }
        __syncthreads();

        // ---- candidate: this thread owns column tid of the 512 cand outputs
        float acc = 0.0f;
        for (int k = 0; k < 512; k += 4) {
            float4 rh4 = *(const float4*)&rh_s[k];
            acc += WtC[(size_t)(k + 0) * 512 + tid] * rh4.x;
            acc += WtC[(size_t)(k + 1) * 512 + tid] * rh4.y;
            acc += WtC[(size_t)(k + 2) * 512 + tid] * rh4.z;
            acc += WtC[(size_t)(k + 3) * 512 + tid] * rh4.w;
        }
        float c  = tanhf_(acc + prow[1024 + tid]);
        float z  = z_s[tid];
        float hp = h_s[tid];
        float hn = (1.0f - z) * hp + z * c;
        h_s[tid] = hn;                         // only this thread reads/writes h_s[tid] here
        out[((size_t)b * Lsz + (t0 + t)) * Hsz + tid] = hn;
        if (t0 + t == Lsz - 1) hlast[b * Hsz + tid] = hn;
        __syncthreads();
    }
    hstate[b * 512 + tid] = h_s[tid];
}

// ---------------------------------------------------------------------------
extern "C" void kernel_launch(void* const* d_in, const int* in_sizes, int n_in,
                              void* d_out, int out_size, void* d_ws, size_t ws_size,
                              hipStream_t stream) {
    const float* x     = (const float*)d_in[0];
    const float* h0    = (const float*)d_in[1];
    const float* W_ru  = (const float*)d_in[2];
    const float* b_ru  = (const float*)d_in[3];
    const float* W_c   = (const float*)d_in[4];
    const float* b_c   = (const float*)d_in[5];
    float* out   = (float*)d_out;
    float* hlast = out + (size_t)Bsz * Lsz * Hsz;

    float* ws     = (float*)d_ws;
    float* WtR    = ws;                         // 512*1024
    float* WtC    = WtR + 512 * 1024;           // 512*512
    float* hstate = WtC + 512 * 512;            // 32*512
    float* pre    = hstate + Bsz * Hsz;         // Tc*32*1536

    // pick largest chunk length that fits the workspace
    const size_t fixed_bytes = (size_t)(512 * 1024 + 512 * 512 + Bsz * Hsz) * 4;
    int Tc = 256;
    while (Tc > 8 && fixed_bytes + (size_t)Tc * Bsz * NG * 4 > ws_size) Tc >>= 1;

    transpose_k<<<dim3(32, 16), 256, 0, stream>>>(W_ru, WtR, 1024, 512, 1024);
    transpose_k<<<dim3(16, 16), 256, 0, stream>>>(W_c,  WtC,  512, 512, 1024);
    init_h<<<(Bsz * Hsz) / 256, 256, 0, stream>>>(h0, hstate);

    const int nchunks = Lsz / Tc;
    for (int cidx = 0; cidx < nchunks; ++cidx) {
        const int t0 = cidx * Tc;
        gemm_pre<<<dim3((Tc * Bsz) / 128, NG / 128), 256, 0, stream>>>(
            x, W_ru, b_ru, W_c, b_c, pre, t0);
        gru_rec<<<Bsz, 512, 0, stream>>>(WtR, WtC, pre, hstate, out, hlast, t0, Tc);
    }
}